// Round 1
// baseline (1237.686 us; speedup 1.0000x reference)
//
#include <hip/hip_runtime.h>

typedef __attribute__((ext_vector_type(4))) float fx4;
typedef __attribute__((ext_vector_type(8))) unsigned short u16x8;
typedef __attribute__((ext_vector_type(8))) __bf16 bf16x8;

static __device__ __forceinline__ unsigned short f2bf(float f) {
  unsigned int u = __builtin_bit_cast(unsigned int, f);
  u += 0x7fffu + ((u >> 16) & 1u);          // round-to-nearest-even
  return (unsigned short)(u >> 16);
}
static __device__ __forceinline__ float bf2f(unsigned short s) {
  unsigned int u = ((unsigned int)s) << 16;
  return __builtin_bit_cast(float, u);
}
static __device__ __forceinline__ fx4 mfma16(u16x8 a, u16x8 b, fx4 c) {
  return __builtin_amdgcn_mfma_f32_16x16x32_bf16(
      __builtin_bit_cast(bf16x8, a), __builtin_bit_cast(bf16x8, b), c, 0, 0, 0);
}

// Swizzled ushort-index helpers for LDS tiles (kills ds_read_b128 bank conflicts,
// keeps 16B blocks contiguous: XOR only flips which 8-col group we land in).
static __device__ __forceinline__ int swz128(int row, int col) {  // [rows][128] bf16
  return row * 128 + (col ^ ((row & 7) << 3));
}
static __device__ __forceinline__ int swz32(int row, int col) {   // [rows][32] bf16
  return row * 32 + (col ^ (((row >> 1) & 3) << 3));
}

// ---- ws layout (ushort units): weights bf16, transposed to [N][Kpad] ----
#define WT_FE1 0        // [128][32]  (fe_W1, K=18 pad 32)
#define WT_FE2 4096     // [128][128] (fe_W2)
#define WT_EE1 20480    // [128][32]  (ee_W1, K=4 pad 32)
#define WT_EE2 24576    // [128][128] (ee_W2)
#define WT_A   40960    // [128][128] (ie_W1 rows 0..127   : sr_sum)
#define WT_B   57344    // [128][128] (ie_W1 rows 128..255 : node_sum)
#define WT_C   73728    // [128][128] (ie_W1 rows 256..383 : edge_latent)
#define WT_IE2 90112    // [128][128] (ie_W2)
#define WT_TOTAL 106496

__global__ void prep_weights(const float* __restrict__ feW1, const float* __restrict__ feW2,
                             const float* __restrict__ eeW1, const float* __restrict__ eeW2,
                             const float* __restrict__ ieW1, const float* __restrict__ ieW2,
                             unsigned short* __restrict__ wt) {
  int i = blockIdx.x * 256 + threadIdx.x;
  if (i >= WT_TOTAL) return;
  unsigned short v;
  if (i < WT_FE2)      { int n = i >> 5, k = i & 31; v = (k < 18) ? f2bf(feW1[k * 128 + n]) : 0; }
  else if (i < WT_EE1) { int j = i - WT_FE2; int n = j >> 7, k = j & 127; v = f2bf(feW2[k * 128 + n]); }
  else if (i < WT_EE2) { int j = i - WT_EE1; int n = j >> 5, k = j & 31; v = (k < 4) ? f2bf(eeW1[k * 128 + n]) : 0; }
  else if (i < WT_A)   { int j = i - WT_EE2; int n = j >> 7, k = j & 127; v = f2bf(eeW2[k * 128 + n]); }
  else if (i < WT_B)   { int j = i - WT_A;   int n = j >> 7, k = j & 127; v = f2bf(ieW1[k * 128 + n]); }
  else if (i < WT_C)   { int j = i - WT_B;   int n = j >> 7, k = j & 127; v = f2bf(ieW1[(128 + k) * 128 + n]); }
  else if (i < WT_IE2) { int j = i - WT_C;   int n = j >> 7, k = j & 127; v = f2bf(ieW1[(256 + k) * 128 + n]); }
  else                 { int j = i - WT_IE2; int n = j >> 7, k = j & 127; v = f2bf(ieW2[k * 128 + n]); }
  wt[i] = v;
}

struct Params {
  const int* eidx;
  const float* dx; const float* attr;
  const float* basis[3];
  const float* sv[6]; const float* rv[6];
  const float* nl;
  const float* fe_b1; const float* fe_b2; const float* fe_g; const float* fe_be;
  const float* ee_b1; const float* ee_b2; const float* ee_g; const float* ee_be;
  const float* ie_b1; const float* ie_b2; const float* ie_g; const float* ie_be;
  const unsigned short* wt;
  float* out;
  int E;
};

// GEMM: A from LDS ([rows][KPAD] swizzled bf16), B from global ws ([128][KPAD] bf16),
// accumulates into acc[MT][8] covering rows [rowbase, rowbase+16*MT) x 128 cols.
template<int KPAD, int MT, int KT>
static __device__ __forceinline__ void gemm_acc(const unsigned short* As, int rowbase,
                                                const unsigned short* __restrict__ Bg,
                                                fx4 (*acc)[8], int l16, int lgr) {
#pragma unroll
  for (int kk = 0; kk < KT; kk++) {
    const int k0 = kk * 32 + lgr * 8;
    u16x8 af[MT];
#pragma unroll
    for (int mt = 0; mt < MT; mt++) {
      int row = rowbase + mt * 16 + l16;
      int idx = (KPAD == 32) ? swz32(row, k0) : swz128(row, k0);
      af[mt] = *(const u16x8*)(As + idx);
    }
#pragma unroll
    for (int nt = 0; nt < 8; nt++) {
      int col = nt * 16 + l16;
      u16x8 bf = *(const u16x8*)(Bg + col * KPAD + k0);
#pragma unroll
      for (int mt = 0; mt < MT; mt++) acc[mt][nt] = mfma16(af[mt], bf, acc[mt][nt]);
    }
  }
}

__global__ __launch_bounds__(256) void fused(Params p) {
  __shared__ unsigned short featbuf[128 * 32];  // fe features (s rows 0..63, r rows 64..127)
  __shared__ unsigned short eebuf[64 * 32];     // ee inputs  (K=4 pad 32)
  __shared__ unsigned short big[128 * 128];     // B: fe h1 + fe LN out; C/D: rows0-63 h1e/h1i, rows64-127 node_sum
  __shared__ unsigned short srbuf[64 * 128];    // s_lat + r_lat (bf16)
  __shared__ unsigned short elbuf[64 * 128];    // edge_latent (bf16)

  const int tid = threadIdx.x;
  const int wave = tid >> 6, lane = tid & 63;
  const int l16 = lane & 15, lgr = lane >> 4;
  const int e0 = blockIdx.x * 64;
  const unsigned short* wt = p.wt;
  const fx4 z4 = {0.f, 0.f, 0.f, 0.f};

  // ---------------- Phase A: features ----------------
  for (int i = tid; i < 128 * 32; i += 256) featbuf[i] = 0;
  for (int i = tid; i < 64 * 32; i += 256) eebuf[i] = 0;
  __syncthreads();
  {
    const int row = tid >> 1, half = tid & 1;
    const int e = e0 + (row & 63);
    const bool isR = row >= 64;
    float bx[3][3];
#pragma unroll
    for (int i = 0; i < 3; i++) {
      const float* bp = p.basis[i] + 3 * (size_t)e;
      bx[i][0] = bp[0]; bx[i][1] = bp[1]; bx[i][2] = bp[2];
    }
    const float sgn_tab[6] = {-1.f, -1.f, -1.f, 1.f, -1.f, 1.f};
#pragma unroll
    for (int kk = 0; kk < 3; kk++) {
      int k = half * 3 + kk;
      const float* vp = (isR ? p.rv[k] : p.sv[k]) + 3 * (size_t)e;
      float v0 = vp[0], v1 = vp[1], v2 = vp[2];
      float sgn = isR ? sgn_tab[k] : 1.f;
#pragma unroll
      for (int i = 0; i < 3; i++) {
        float d = (bx[i][0] * v0 + bx[i][1] * v1 + bx[i][2] * v2) * sgn;
        featbuf[swz32(row, k * 3 + i)] = f2bf(d);
      }
    }
  }
  if (tid < 64) {
    int e2 = e0 + tid;
    float d0 = p.dx[3 * e2], d1 = p.dx[3 * e2 + 1], d2 = p.dx[3 * e2 + 2];
    eebuf[swz32(tid, 0)] = f2bf(sqrtf(d0 * d0 + d1 * d1 + d2 * d2));
    eebuf[swz32(tid, 1)] = f2bf(p.attr[3 * e2]);
    eebuf[swz32(tid, 2)] = f2bf(p.attr[3 * e2 + 1]);
    eebuf[swz32(tid, 3)] = f2bf(p.attr[3 * e2 + 2]);
  }
  __syncthreads();

  // ---------------- Phase B: fe MLP, 128 rows (wave w owns rows 32w..32w+31) ----
  {
    fx4 acc[2][8];
#pragma unroll
    for (int a = 0; a < 2; a++)
#pragma unroll
      for (int b = 0; b < 8; b++) acc[a][b] = z4;
    gemm_acc<32, 2, 1>(featbuf, wave * 32, wt + WT_FE1, acc, l16, lgr);
#pragma unroll
    for (int mt = 0; mt < 2; mt++)
#pragma unroll
      for (int nt = 0; nt < 8; nt++) {
        int col = nt * 16 + l16;
        float b = p.fe_b1[col];
#pragma unroll
        for (int r = 0; r < 4; r++) {
          int row = wave * 32 + mt * 16 + lgr * 4 + r;
          float v = acc[mt][nt][r] + b;
          big[swz128(row, col)] = f2bf(v > 0.f ? v : 0.f);
        }
      }
  }
  {
    fx4 acc[2][8];
#pragma unroll
    for (int a = 0; a < 2; a++)
#pragma unroll
      for (int b = 0; b < 8; b++) acc[a][b] = z4;
    gemm_acc<128, 2, 4>(big, wave * 32, wt + WT_FE2, acc, l16, lgr);
#pragma unroll
    for (int mt = 0; mt < 2; mt++) {
      float sum[4] = {0, 0, 0, 0}, sq[4] = {0, 0, 0, 0};
#pragma unroll
      for (int nt = 0; nt < 8; nt++) {
        int col = nt * 16 + l16;
        float b = p.fe_b2[col];
#pragma unroll
        for (int r = 0; r < 4; r++) {
          float v = acc[mt][nt][r] + b; acc[mt][nt][r] = v;
          sum[r] += v; sq[r] += v * v;
        }
      }
      float mu[4], rs[4];
#pragma unroll
      for (int r = 0; r < 4; r++) {
        float s_ = sum[r], q_ = sq[r];
        for (int m = 1; m < 16; m <<= 1) { s_ += __shfl_xor(s_, m, 64); q_ += __shfl_xor(q_, m, 64); }
        mu[r] = s_ * (1.f / 128.f);
        float var = q_ * (1.f / 128.f) - mu[r] * mu[r];
        rs[r] = rsqrtf(var + 1e-5f);
      }
#pragma unroll
      for (int nt = 0; nt < 8; nt++) {
        int col = nt * 16 + l16;
        float gg = p.fe_g[col], bb = p.fe_be[col];
#pragma unroll
        for (int r = 0; r < 4; r++) {
          int row = wave * 32 + mt * 16 + lgr * 4 + r;
          float o = (acc[mt][nt][r] - mu[r]) * rs[r] * gg + bb;
          big[swz128(row, col)] = f2bf(o);
        }
      }
    }
  }
  __syncthreads();  // cross-wave: srbuf build reads rows written by other waves

  // ---- srbuf = s_lat + r_lat (wave-local rows from here on) ----
  {
    int e = tid >> 2, q = tid & 3;
#pragma unroll
    for (int c = q * 32; c < q * 32 + 32; c += 8) {
      u16x8 a = *(const u16x8*)(big + swz128(e, c));
      u16x8 b = *(const u16x8*)(big + swz128(64 + e, c));
      u16x8 o;
#pragma unroll
      for (int j = 0; j < 8; j++) o[j] = f2bf(bf2f(a[j]) + bf2f(b[j]));
      *(u16x8*)(srbuf + swz128(e, c)) = o;
    }
  }
  // ---- node_sum gather -> big rows 64..127 (bf16) ----
  {
    int e = tid >> 2, q = tid & 3;
    int s = p.eidx[e0 + e], r = p.eidx[p.E + e0 + e];
    const float* ns = p.nl + (size_t)s * 128;
    const float* nr = p.nl + (size_t)r * 128;
#pragma unroll
    for (int c = q * 32; c < q * 32 + 32; c += 8) {
      fx4 a0 = *(const fx4*)(ns + c), a1 = *(const fx4*)(ns + c + 4);
      fx4 b0 = *(const fx4*)(nr + c), b1 = *(const fx4*)(nr + c + 4);
      u16x8 o;
#pragma unroll
      for (int j = 0; j < 4; j++) { o[j] = f2bf(a0[j] + b0[j]); o[4 + j] = f2bf(a1[j] + b1[j]); }
      *(u16x8*)(big + swz128(64 + e, c)) = o;
    }
  }

  // ---------------- Phase C: ee MLP, 64 rows (wave w owns rows 16w..16w+15) ----
  {
    fx4 acc[1][8];
#pragma unroll
    for (int b = 0; b < 8; b++) acc[0][b] = z4;
    gemm_acc<32, 1, 1>(eebuf, wave * 16, wt + WT_EE1, acc, l16, lgr);
#pragma unroll
    for (int nt = 0; nt < 8; nt++) {
      int col = nt * 16 + l16;
      float b = p.ee_b1[col];
#pragma unroll
      for (int r = 0; r < 4; r++) {
        int row = wave * 16 + lgr * 4 + r;
        float v = acc[0][nt][r] + b;
        big[swz128(row, col)] = f2bf(v > 0.f ? v : 0.f);
      }
    }
  }
  {
    fx4 acc[1][8];
#pragma unroll
    for (int b = 0; b < 8; b++) acc[0][b] = z4;
    gemm_acc<128, 1, 4>(big, wave * 16, wt + WT_EE2, acc, l16, lgr);
    float sum[4] = {0, 0, 0, 0}, sq[4] = {0, 0, 0, 0};
#pragma unroll
    for (int nt = 0; nt < 8; nt++) {
      int col = nt * 16 + l16;
      float b = p.ee_b2[col];
#pragma unroll
      for (int r = 0; r < 4; r++) {
        float v = acc[0][nt][r] + b; acc[0][nt][r] = v;
        sum[r] += v; sq[r] += v * v;
      }
    }
    float mu[4], rs[4];
#pragma unroll
    for (int r = 0; r < 4; r++) {
      float s_ = sum[r], q_ = sq[r];
      for (int m = 1; m < 16; m <<= 1) { s_ += __shfl_xor(s_, m, 64); q_ += __shfl_xor(q_, m, 64); }
      mu[r] = s_ * (1.f / 128.f);
      float var = q_ * (1.f / 128.f) - mu[r] * mu[r];
      rs[r] = rsqrtf(var + 1e-5f);
    }
#pragma unroll
    for (int nt = 0; nt < 8; nt++) {
      int col = nt * 16 + l16;
      float gg = p.ee_g[col], bb = p.ee_be[col];
#pragma unroll
      for (int r = 0; r < 4; r++) {
        int row = wave * 16 + lgr * 4 + r;
        float o = (acc[0][nt][r] - mu[r]) * rs[r] * gg + bb;
        elbuf[swz128(row, col)] = f2bf(o);
      }
    }
  }

  // ---------------- Phase D: ie layer1 (3 GEMMs K=128) + ReLU ----------------
  {
    fx4 acc[1][8];
#pragma unroll
    for (int b = 0; b < 8; b++) acc[0][b] = z4;
    gemm_acc<128, 1, 4>(srbuf, wave * 16, wt + WT_A, acc, l16, lgr);
    gemm_acc<128, 1, 4>(elbuf, wave * 16, wt + WT_C, acc, l16, lgr);
    gemm_acc<128, 1, 4>(big, 64 + wave * 16, wt + WT_B, acc, l16, lgr);
#pragma unroll
    for (int nt = 0; nt < 8; nt++) {
      int col = nt * 16 + l16;
      float b = p.ie_b1[col];
#pragma unroll
      for (int r = 0; r < 4; r++) {
        int row = wave * 16 + lgr * 4 + r;
        float v = acc[0][nt][r] + b;
        big[swz128(row, col)] = f2bf(v > 0.f ? v : 0.f);
      }
    }
  }
  // ---------------- Phase E: ie layer2 + LN -> out -----------------------
  {
    fx4 acc[1][8];
#pragma unroll
    for (int b = 0; b < 8; b++) acc[0][b] = z4;
    gemm_acc<128, 1, 4>(big, wave * 16, wt + WT_IE2, acc, l16, lgr);
    float sum[4] = {0, 0, 0, 0}, sq[4] = {0, 0, 0, 0};
#pragma unroll
    for (int nt = 0; nt < 8; nt++) {
      int col = nt * 16 + l16;
      float b = p.ie_b2[col];
#pragma unroll
      for (int r = 0; r < 4; r++) {
        float v = acc[0][nt][r] + b; acc[0][nt][r] = v;
        sum[r] += v; sq[r] += v * v;
      }
    }
    float mu[4], rs[4];
#pragma unroll
    for (int r = 0; r < 4; r++) {
      float s_ = sum[r], q_ = sq[r];
      for (int m = 1; m < 16; m <<= 1) { s_ += __shfl_xor(s_, m, 64); q_ += __shfl_xor(q_, m, 64); }
      mu[r] = s_ * (1.f / 128.f);
      float var = q_ * (1.f / 128.f) - mu[r] * mu[r];
      rs[r] = rsqrtf(var + 1e-5f);
    }
#pragma unroll
    for (int nt = 0; nt < 8; nt++) {
      int col = nt * 16 + l16;
      float gg = p.ie_g[col], bb = p.ie_be[col];
#pragma unroll
      for (int r = 0; r < 4; r++) {
        int row = wave * 16 + lgr * 4 + r;
        float o = (acc[0][nt][r] - mu[r]) * rs[r] * gg + bb;
        p.out[(size_t)(e0 + row) * 128 + col] = o;
      }
    }
  }
}

extern "C" void kernel_launch(void* const* d_in, const int* in_sizes, int n_in,
                              void* d_out, int out_size, void* d_ws, size_t ws_size,
                              hipStream_t stream) {
  (void)n_in; (void)out_size;
  const int E = in_sizes[1] / 3;  // edge_dx_ is [E,3]
  unsigned short* wt = reinterpret_cast<unsigned short*>(d_ws);
  if (ws_size < (size_t)WT_TOTAL * sizeof(unsigned short)) return;

  prep_weights<<<(WT_TOTAL + 255) / 256, 256, 0, stream>>>(
      (const float*)d_in[19], (const float*)d_in[21],
      (const float*)d_in[25], (const float*)d_in[27],
      (const float*)d_in[31], (const float*)d_in[33], wt);

  Params p;
  p.eidx = (const int*)d_in[0];
  p.dx = (const float*)d_in[1];
  p.attr = (const float*)d_in[2];
  for (int i = 0; i < 3; i++) p.basis[i] = (const float*)d_in[3 + i];
  for (int k = 0; k < 6; k++) { p.sv[k] = (const float*)d_in[6 + k]; p.rv[k] = (const float*)d_in[12 + k]; }
  p.nl = (const float*)d_in[18];
  p.fe_b1 = (const float*)d_in[20]; p.fe_b2 = (const float*)d_in[22];
  p.fe_g  = (const float*)d_in[23]; p.fe_be = (const float*)d_in[24];
  p.ee_b1 = (const float*)d_in[26]; p.ee_b2 = (const float*)d_in[28];
  p.ee_g  = (const float*)d_in[29]; p.ee_be = (const float*)d_in[30];
  p.ie_b1 = (const float*)d_in[32]; p.ie_b2 = (const float*)d_in[34];
  p.ie_g  = (const float*)d_in[35]; p.ie_be = (const float*)d_in[36];
  p.wt = wt;
  p.out = (float*)d_out;
  p.E = E;
  fused<<<E / 64, 256, 0, stream>>>(p);
}